// Round 3
// baseline (1704.574 us; speedup 1.0000x reference)
//
#include <hip/hip_runtime.h>

#define F_IN 256
#define CCH  128
#define BSH  7                 // bucket = dst >> 7 (128 nodes per bucket)
#define BNODES 128
#define NBUCK_PAD 1024
#define CHUNK 8192

// ---------------- helpers: bf16 pack/unpack ----------------
__device__ __forceinline__ unsigned short f2bf(float f) {
    union { float f; unsigned i; } u; u.f = f;
    unsigned r = u.i + 0x7fffu + ((u.i >> 16) & 1u);   // RNE
    return (unsigned short)(r >> 16);
}
__device__ __forceinline__ unsigned packbf2(float lo, float hi) {
    return (unsigned)f2bf(lo) | ((unsigned)f2bf(hi) << 16);
}
__device__ __forceinline__ float2 bf2f2(unsigned u) {
    union { unsigned i; float f; } lo, hi;
    lo.i = u << 16;
    hi.i = u & 0xffff0000u;
    return make_float2(lo.f, hi.f);
}

// ---------------- GEMM: C[M,128] = epilogue(A[M,K] @ W[128,K]^T) ----------------
// MODE 0: C = relu(A@W^T + bias) stored fp32 (h)
// MODE 1: C = (A@W^T) * dinv[row]  stored packed bf16x2 (z')
#define BM 128
#define BN 128
#define BK 16
#define TM 8
#define TN 8

template<int MODE>
__global__ __launch_bounds__(256)
void gemm_tiled(const float* __restrict__ A, const float* __restrict__ W,
                const float* __restrict__ bias, const float* __restrict__ dinv,
                float* __restrict__ Cf, unsigned* __restrict__ Cq,
                int M, int Kdim)
{
    __shared__ float As[BK][BM];
    __shared__ float Bs[BK][BN];
    const int tid = threadIdx.x;
    const int tx = tid & 15;
    const int ty = tid >> 4;
    const int m0 = blockIdx.x * BM;

    float acc[TM][TN];
#pragma unroll
    for (int i = 0; i < TM; i++)
#pragma unroll
        for (int j = 0; j < TN; j++) acc[i][j] = 0.f;

    for (int k0 = 0; k0 < Kdim; k0 += BK) {
#pragma unroll
        for (int l = 0; l < 2; l++) {
            int f = tid + l * 256;
            int row = f >> 2, kq = f & 3;
            float4 a;
            if (m0 + row < M)
                a = *reinterpret_cast<const float4*>(&A[(long)(m0 + row) * Kdim + k0 + kq * 4]);
            else
                a = make_float4(0.f, 0.f, 0.f, 0.f);
            As[kq * 4 + 0][row] = a.x;
            As[kq * 4 + 1][row] = a.y;
            As[kq * 4 + 2][row] = a.z;
            As[kq * 4 + 3][row] = a.w;
        }
#pragma unroll
        for (int l = 0; l < 2; l++) {
            int f = tid + l * 256;
            int n = f >> 2, kq = f & 3;
            float4 b = *reinterpret_cast<const float4*>(&W[(long)n * Kdim + k0 + kq * 4]);
            Bs[kq * 4 + 0][n] = b.x;
            Bs[kq * 4 + 1][n] = b.y;
            Bs[kq * 4 + 2][n] = b.z;
            Bs[kq * 4 + 3][n] = b.w;
        }
        __syncthreads();
#pragma unroll
        for (int kk = 0; kk < BK; kk++) {
            float a[TM], b[TN];
            *(float4*)&a[0] = *(const float4*)&As[kk][ty * TM];
            *(float4*)&a[4] = *(const float4*)&As[kk][ty * TM + 4];
            *(float4*)&b[0] = *(const float4*)&Bs[kk][tx * TN];
            *(float4*)&b[4] = *(const float4*)&Bs[kk][tx * TN + 4];
#pragma unroll
            for (int i = 0; i < TM; i++)
#pragma unroll
                for (int j = 0; j < TN; j++) acc[i][j] += a[i] * b[j];
        }
        __syncthreads();
    }

    if (MODE == 0) {
        float bvals[TN];
#pragma unroll
        for (int j = 0; j < TN; j++) bvals[j] = bias[tx * TN + j];
#pragma unroll
        for (int i = 0; i < TM; i++) {
            int m = m0 + ty * TM + i;
            if (m < M) {
                float tmp[TN];
#pragma unroll
                for (int j = 0; j < TN; j++) tmp[j] = fmaxf(acc[i][j] + bvals[j], 0.f);
                *(float4*)&Cf[(long)m * CCH + tx * TN]     = *(float4*)&tmp[0];
                *(float4*)&Cf[(long)m * CCH + tx * TN + 4] = *(float4*)&tmp[4];
            }
        }
    } else {
#pragma unroll
        for (int i = 0; i < TM; i++) {
            int m = m0 + ty * TM + i;
            if (m < M) {
                float di = dinv[m];
                unsigned p[4];
#pragma unroll
                for (int jj = 0; jj < 4; jj++)
                    p[jj] = packbf2(acc[i][2 * jj] * di, acc[i][2 * jj + 1] * di);
                *(uint4*)&Cq[(long)m * (CCH / 2) + tx * 4] = *(uint4*)&p[0];
            }
        }
    }
}

// ---------------- bucket build ----------------
__global__ void zero1024(int* g) { g[threadIdx.x] = 0; }

__global__ __launch_bounds__(256)
void hist_kernel(const int* __restrict__ dst, int* __restrict__ ghist, int E)
{
    __shared__ int h[NBUCK_PAD];
    int t = threadIdx.x;
    for (int i = t; i < NBUCK_PAD; i += 256) h[i] = 0;
    __syncthreads();
    int cb = blockIdx.x * CHUNK;
    int ce = min(cb + CHUNK, E);
    for (int e = cb + t; e < ce; e += 256)
        atomicAdd(&h[dst[e] >> BSH], 1);
    __syncthreads();
    for (int i = t; i < NBUCK_PAD; i += 256)
        if (h[i]) atomicAdd(&ghist[i], h[i]);
}

__global__ void scan1024(const int* __restrict__ ghist, int* __restrict__ base,
                         int* __restrict__ cursor)
{
    __shared__ int s[NBUCK_PAD];
    int t = threadIdx.x;   // 1024 threads
    int v = ghist[t];
    s[t] = v;
    __syncthreads();
    for (int off = 1; off < 1024; off <<= 1) {
        int x = (t >= off) ? s[t - off] : 0;
        __syncthreads();
        s[t] += x;
        __syncthreads();
    }
    int excl = s[t] - v;
    base[t] = excl;
    cursor[t] = excl;
    if (t == 1023) base[1024] = s[t];
}

__global__ __launch_bounds__(256)
void partition_kernel(const int* __restrict__ src, const int* __restrict__ dst,
                      int* __restrict__ cursor, unsigned* __restrict__ pairs, int E)
{
    __shared__ int lhist[NBUCK_PAD];    // reused as local cursor after reservation
    __shared__ int lbase[NBUCK_PAD];
    __shared__ int rbase[NBUCK_PAD];
    __shared__ int ssum[256];
    __shared__ uint2 staged[CHUNK];     // 64 KB
    int t = threadIdx.x;
    for (int i = t; i < NBUCK_PAD; i += 256) lhist[i] = 0;
    __syncthreads();
    int cb = blockIdx.x * CHUNK;
    int ce = min(cb + CHUNK, E);
    for (int e = cb + t; e < ce; e += 256)
        atomicAdd(&lhist[dst[e] >> BSH], 1);
    __syncthreads();
    // block scan of 1024 hist with 256 threads (4 each)
    int a0 = lhist[4 * t], a1 = lhist[4 * t + 1], a2 = lhist[4 * t + 2], a3 = lhist[4 * t + 3];
    int tsum = a0 + a1 + a2 + a3;
    ssum[t] = tsum;
    __syncthreads();
    for (int off = 1; off < 256; off <<= 1) {
        int x = (t >= off) ? ssum[t - off] : 0;
        __syncthreads();
        ssum[t] += x;
        __syncthreads();
    }
    int texcl = ssum[t] - tsum;
    lbase[4 * t]     = texcl;
    lbase[4 * t + 1] = texcl + a0;
    lbase[4 * t + 2] = texcl + a0 + a1;
    lbase[4 * t + 3] = texcl + a0 + a1 + a2;
    // reserve global runs; zero local cursors (reuse lhist)
    for (int i = t; i < NBUCK_PAD; i += 256) {
        int c = lhist[i];
        rbase[i] = c ? atomicAdd(&cursor[i], c) : 0;
        lhist[i] = 0;
    }
    __syncthreads();
    // stage sorted-by-bucket
    for (int e = cb + t; e < ce; e += 256) {
        int d = dst[e];
        int b = d >> BSH;
        unsigned packed = ((unsigned)src[e] << BSH) | (unsigned)(d & (BNODES - 1));
        int p = lbase[b] + atomicAdd(&lhist[b], 1);
        staged[p] = make_uint2(packed, (unsigned)b);
    }
    __syncthreads();
    // coalesced write-out of bucket runs
    int cnt = ce - cb;
    for (int i = t; i < cnt; i += 256) {
        uint2 sp = staged[i];
        int b = (int)sp.y;
        pairs[rbase[b] + (i - lbase[b])] = sp.x;
    }
}

__global__ __launch_bounds__(256)
void degree_kernel(const unsigned* __restrict__ pairs, const int* __restrict__ base,
                   float* __restrict__ dinv, int N)
{
    __shared__ int deg[BNODES];
    int b = blockIdx.x, t = threadIdx.x;
    if (t < BNODES) deg[t] = 0;
    __syncthreads();
    int rb = base[b], re = base[b + 1];
    for (int e = rb + t; e < re; e += 256)
        atomicAdd(&deg[pairs[e] & (BNODES - 1)], 1);
    __syncthreads();
    int n0 = b << BSH;
    if (t < BNODES && n0 + t < N)
        dinv[n0 + t] = rsqrtf((float)deg[t] + 1.0f);
}

// ---------------- bucket gather: out[n] = b2 + dinv[n]*(z'[n] + sum_in z'[s]) ----------------
__global__ __launch_bounds__(256)
void bucket_gather(const unsigned* __restrict__ pairs, const int* __restrict__ base,
                   const unsigned* __restrict__ zq, const float* __restrict__ dinv,
                   const float* __restrict__ b2, float* __restrict__ out, int N)
{
    __shared__ float acc[BNODES][CCH];   // 64 KB
    const int t = threadIdx.x, w = t >> 6, lane = t & 63;
    for (int i = t; i < BNODES * CCH / 4; i += 256)
        ((float4*)acc)[i] = make_float4(0.f, 0.f, 0.f, 0.f);
    __syncthreads();

    const int b = blockIdx.x;
    const int rb = base[b], re = base[b + 1];
    const int nw = re - rb;
    const int per = (nw + 3) >> 2;
    const int ws = rb + w * per;
    const int we = min(ws + per, re);

    int e = ws;
    for (; e + 4 <= we; e += 4) {
        unsigned p0 = pairs[e], p1 = pairs[e + 1], p2 = pairs[e + 2], p3 = pairs[e + 3];
        unsigned z0 = zq[(long)(p0 >> BSH) * 64 + lane];
        unsigned z1 = zq[(long)(p1 >> BSH) * 64 + lane];
        unsigned z2 = zq[(long)(p2 >> BSH) * 64 + lane];
        unsigned z3 = zq[(long)(p3 >> BSH) * 64 + lane];
        float2 f0 = bf2f2(z0), f1 = bf2f2(z1), f2 = bf2f2(z2), f3 = bf2f2(z3);
        int l0 = p0 & (BNODES - 1), l1 = p1 & (BNODES - 1);
        int l2 = p2 & (BNODES - 1), l3 = p3 & (BNODES - 1);
        atomicAdd(&acc[l0][2 * lane], f0.x); atomicAdd(&acc[l0][2 * lane + 1], f0.y);
        atomicAdd(&acc[l1][2 * lane], f1.x); atomicAdd(&acc[l1][2 * lane + 1], f1.y);
        atomicAdd(&acc[l2][2 * lane], f2.x); atomicAdd(&acc[l2][2 * lane + 1], f2.y);
        atomicAdd(&acc[l3][2 * lane], f3.x); atomicAdd(&acc[l3][2 * lane + 1], f3.y);
    }
    for (; e < we; e++) {
        unsigned p = pairs[e];
        unsigned z = zq[(long)(p >> BSH) * 64 + lane];
        float2 f = bf2f2(z);
        int l = p & (BNODES - 1);
        atomicAdd(&acc[l][2 * lane], f.x);
        atomicAdd(&acc[l][2 * lane + 1], f.y);
    }
    __syncthreads();

    const int n0 = b << BSH;
    const int nlim = min(BNODES, N - n0);
    float bb0 = b2[2 * lane], bb1 = b2[2 * lane + 1];
    for (int ld = w; ld < nlim; ld += 4) {
        int node = n0 + ld;
        float2 self = bf2f2(zq[(long)node * 64 + lane]);
        float di = dinv[node];
        float2 o;
        o.x = bb0 + di * (acc[ld][2 * lane]     + self.x);
        o.y = bb1 + di * (acc[ld][2 * lane + 1] + self.y);
        *(float2*)&out[(long)node * CCH + 2 * lane] = o;
    }
}

extern "C" void kernel_launch(void* const* d_in, const int* in_sizes, int n_in,
                              void* d_out, int out_size, void* d_ws, size_t ws_size,
                              hipStream_t stream)
{
    const float* x  = (const float*)d_in[0];
    const int*   ei = (const int*)d_in[1];
    const float* W1 = (const float*)d_in[2];
    const float* b1 = (const float*)d_in[3];
    const float* W2 = (const float*)d_in[4];
    const float* b2 = (const float*)d_in[5];
    float* out = (float*)d_out;

    const int N = in_sizes[0] / F_IN;
    const int E = in_sizes[1] / 2;
    const int* src = ei;
    const int* dst = ei + E;

    char* ws = (char*)d_ws;
    float* h      = (float*)ws;    ws += (size_t)N * CCH * 4;
    unsigned* zq  = (unsigned*)ws; ws += (size_t)N * (CCH / 2) * 4;
    unsigned* prs = (unsigned*)ws; ws += (size_t)E * 4;
    float* dinv   = (float*)ws;    ws += (size_t)N * 4;
    int* ghist    = (int*)ws;      ws += NBUCK_PAD * 4;
    int* gbase    = (int*)ws;      ws += (NBUCK_PAD + 1) * 4;
    int* gcursor  = (int*)ws;      ws += NBUCK_PAD * 4;

    const int nchunks = (E + CHUNK - 1) / CHUNK;     // 196
    const int nbuck   = (N + BNODES - 1) / BNODES;   // 782

    // bucket build
    zero1024<<<1, 1024, 0, stream>>>(ghist);
    hist_kernel<<<nchunks, 256, 0, stream>>>(dst, ghist, E);
    scan1024<<<1, 1024, 0, stream>>>(ghist, gbase, gcursor);
    partition_kernel<<<nchunks, 256, 0, stream>>>(src, dst, gcursor, prs, E);
    degree_kernel<<<nbuck, 256, 0, stream>>>(prs, gbase, dinv, N);

    // h = relu(x @ W1^T + b1)  [fp32]
    gemm_tiled<0><<<(N + BM - 1) / BM, 256, 0, stream>>>(x, W1, b1, nullptr, h, nullptr, N, F_IN);
    // z' = (h @ W2^T) * dinv   [packed bf16]
    gemm_tiled<1><<<(N + BM - 1) / BM, 256, 0, stream>>>(h, W2, nullptr, dinv, nullptr, zq, N, CCH);

    // aggregate per bucket
    bucket_gather<<<nbuck, 256, 0, stream>>>(prs, gbase, zq, dinv, b2, out, N);
}

// Round 4
// 445.188 us; speedup vs baseline: 3.8289x; 3.8289x over previous
//
#include <hip/hip_runtime.h>

#define F_IN 256
#define CCH  128
#define BSH  7                 // bucket = dst >> 7 (128 nodes per bucket)
#define BNODES 128
#define NBUCK_PAD 1024
#define CHUNK 8192

// ---------------- helpers: bf16 pack/unpack ----------------
__device__ __forceinline__ unsigned short f2bf(float f) {
    union { float f; unsigned i; } u; u.f = f;
    unsigned r = u.i + 0x7fffu + ((u.i >> 16) & 1u);   // RNE
    return (unsigned short)(r >> 16);
}
__device__ __forceinline__ unsigned packbf2(float lo, float hi) {
    return (unsigned)f2bf(lo) | ((unsigned)f2bf(hi) << 16);
}
__device__ __forceinline__ float2 bf2f2(unsigned u) {
    union { unsigned i; float f; } lo, hi;
    lo.i = u << 16;
    hi.i = u & 0xffff0000u;
    return make_float2(lo.f, hi.f);
}

// ---------------- GEMM: C[M,128] = epilogue(A[M,K] @ W[128,K]^T) ----------------
// MODE 0: C = relu(A@W^T + bias) stored fp32 (h)
// MODE 1: C = (A@W^T) * dinv[row]  stored packed bf16x2 (z')
#define BM 128
#define BN 128
#define BK 16
#define TM 8
#define TN 8

template<int MODE>
__global__ __launch_bounds__(256)
void gemm_tiled(const float* __restrict__ A, const float* __restrict__ W,
                const float* __restrict__ bias, const float* __restrict__ dinv,
                float* __restrict__ Cf, unsigned* __restrict__ Cq,
                int M, int Kdim)
{
    __shared__ float As[BK][BM];
    __shared__ float Bs[BK][BN];
    const int tid = threadIdx.x;
    const int tx = tid & 15;
    const int ty = tid >> 4;
    const int m0 = blockIdx.x * BM;

    float acc[TM][TN];
#pragma unroll
    for (int i = 0; i < TM; i++)
#pragma unroll
        for (int j = 0; j < TN; j++) acc[i][j] = 0.f;

    for (int k0 = 0; k0 < Kdim; k0 += BK) {
#pragma unroll
        for (int l = 0; l < 2; l++) {
            int f = tid + l * 256;
            int row = f >> 2, kq = f & 3;
            float4 a;
            if (m0 + row < M)
                a = *reinterpret_cast<const float4*>(&A[(long)(m0 + row) * Kdim + k0 + kq * 4]);
            else
                a = make_float4(0.f, 0.f, 0.f, 0.f);
            As[kq * 4 + 0][row] = a.x;
            As[kq * 4 + 1][row] = a.y;
            As[kq * 4 + 2][row] = a.z;
            As[kq * 4 + 3][row] = a.w;
        }
#pragma unroll
        for (int l = 0; l < 2; l++) {
            int f = tid + l * 256;
            int n = f >> 2, kq = f & 3;
            float4 b = *reinterpret_cast<const float4*>(&W[(long)n * Kdim + k0 + kq * 4]);
            Bs[kq * 4 + 0][n] = b.x;
            Bs[kq * 4 + 1][n] = b.y;
            Bs[kq * 4 + 2][n] = b.z;
            Bs[kq * 4 + 3][n] = b.w;
        }
        __syncthreads();
#pragma unroll
        for (int kk = 0; kk < BK; kk++) {
            float a[TM], b[TN];
            *(float4*)&a[0] = *(const float4*)&As[kk][ty * TM];
            *(float4*)&a[4] = *(const float4*)&As[kk][ty * TM + 4];
            *(float4*)&b[0] = *(const float4*)&Bs[kk][tx * TN];
            *(float4*)&b[4] = *(const float4*)&Bs[kk][tx * TN + 4];
#pragma unroll
            for (int i = 0; i < TM; i++)
#pragma unroll
                for (int j = 0; j < TN; j++) acc[i][j] += a[i] * b[j];
        }
        __syncthreads();
    }

    if (MODE == 0) {
        float bvals[TN];
#pragma unroll
        for (int j = 0; j < TN; j++) bvals[j] = bias[tx * TN + j];
#pragma unroll
        for (int i = 0; i < TM; i++) {
            int m = m0 + ty * TM + i;
            if (m < M) {
                float tmp[TN];
#pragma unroll
                for (int j = 0; j < TN; j++) tmp[j] = fmaxf(acc[i][j] + bvals[j], 0.f);
                *(float4*)&Cf[(long)m * CCH + tx * TN]     = *(float4*)&tmp[0];
                *(float4*)&Cf[(long)m * CCH + tx * TN + 4] = *(float4*)&tmp[4];
            }
        }
    } else {
#pragma unroll
        for (int i = 0; i < TM; i++) {
            int m = m0 + ty * TM + i;
            if (m < M) {
                float di = dinv[m];
                unsigned p[4];
#pragma unroll
                for (int jj = 0; jj < 4; jj++)
                    p[jj] = packbf2(acc[i][2 * jj] * di, acc[i][2 * jj + 1] * di);
                *(uint4*)&Cq[(long)m * (CCH / 2) + tx * 4] = *(uint4*)&p[0];
            }
        }
    }
}

// ---------------- bucket build ----------------
__global__ void zero1024(int* g) { g[threadIdx.x] = 0; }

__global__ __launch_bounds__(256)
void hist_kernel(const int* __restrict__ dst, int* __restrict__ ghist, int E)
{
    __shared__ int h[NBUCK_PAD];
    int t = threadIdx.x;
    for (int i = t; i < NBUCK_PAD; i += 256) h[i] = 0;
    __syncthreads();
    int cb = blockIdx.x * CHUNK;
    int ce = min(cb + CHUNK, E);
    for (int e = cb + t; e < ce; e += 256)
        atomicAdd(&h[dst[e] >> BSH], 1);
    __syncthreads();
    for (int i = t; i < NBUCK_PAD; i += 256)
        if (h[i]) atomicAdd(&ghist[i], h[i]);
}

__global__ void scan1024(const int* __restrict__ ghist, int* __restrict__ base,
                         int* __restrict__ cursor)
{
    __shared__ int s[NBUCK_PAD];
    int t = threadIdx.x;   // 1024 threads
    int v = ghist[t];
    s[t] = v;
    __syncthreads();
    for (int off = 1; off < 1024; off <<= 1) {
        int x = (t >= off) ? s[t - off] : 0;
        __syncthreads();
        s[t] += x;
        __syncthreads();
    }
    int excl = s[t] - v;
    base[t] = excl;
    cursor[t] = excl;
    if (t == 1023) base[1024] = s[t];
}

__global__ __launch_bounds__(256)
void partition_kernel(const int* __restrict__ src, const int* __restrict__ dst,
                      int* __restrict__ cursor, unsigned* __restrict__ pairs, int E)
{
    __shared__ int lhist[NBUCK_PAD];    // reused as local cursor after reservation
    __shared__ int lbase[NBUCK_PAD];
    __shared__ int rbase[NBUCK_PAD];
    __shared__ int ssum[256];
    __shared__ uint2 staged[CHUNK];     // 64 KB
    int t = threadIdx.x;
    for (int i = t; i < NBUCK_PAD; i += 256) lhist[i] = 0;
    __syncthreads();
    int cb = blockIdx.x * CHUNK;
    int ce = min(cb + CHUNK, E);
    for (int e = cb + t; e < ce; e += 256)
        atomicAdd(&lhist[dst[e] >> BSH], 1);
    __syncthreads();
    // block scan of 1024 hist with 256 threads (4 each)
    int a0 = lhist[4 * t], a1 = lhist[4 * t + 1], a2 = lhist[4 * t + 2], a3 = lhist[4 * t + 3];
    int tsum = a0 + a1 + a2 + a3;
    ssum[t] = tsum;
    __syncthreads();
    for (int off = 1; off < 256; off <<= 1) {
        int x = (t >= off) ? ssum[t - off] : 0;
        __syncthreads();
        ssum[t] += x;
        __syncthreads();
    }
    int texcl = ssum[t] - tsum;
    lbase[4 * t]     = texcl;
    lbase[4 * t + 1] = texcl + a0;
    lbase[4 * t + 2] = texcl + a0 + a1;
    lbase[4 * t + 3] = texcl + a0 + a1 + a2;
    // reserve global runs; zero local cursors (reuse lhist)
    for (int i = t; i < NBUCK_PAD; i += 256) {
        int c = lhist[i];
        rbase[i] = c ? atomicAdd(&cursor[i], c) : 0;
        lhist[i] = 0;
    }
    __syncthreads();
    // stage sorted-by-bucket
    for (int e = cb + t; e < ce; e += 256) {
        int d = dst[e];
        int b = d >> BSH;
        unsigned packed = ((unsigned)src[e] << BSH) | (unsigned)(d & (BNODES - 1));
        int p = lbase[b] + atomicAdd(&lhist[b], 1);
        staged[p] = make_uint2(packed, (unsigned)b);
    }
    __syncthreads();
    // coalesced write-out of bucket runs
    int cnt = ce - cb;
    for (int i = t; i < cnt; i += 256) {
        uint2 sp = staged[i];
        int b = (int)sp.y;
        pairs[rbase[b] + (i - lbase[b])] = sp.x;
    }
}

// ---------------- per-bucket CSR finalize: degrees, row_start, dinv, node-sorted csr ----------------
__global__ __launch_bounds__(256)
void bucket_csr(const unsigned* __restrict__ pairs, const int* __restrict__ base,
                int* __restrict__ row_start, float* __restrict__ dinv,
                unsigned* __restrict__ csr, int N, int E)
{
    __shared__ int deg[BNODES];
    __shared__ int s[BNODES];
    __shared__ int cur[BNODES];
    const int b = blockIdx.x, t = threadIdx.x;
    if (t < BNODES) deg[t] = 0;
    __syncthreads();
    const int rb = base[b], re = base[b + 1];
    for (int e = rb + t; e < re; e += 256)
        atomicAdd(&deg[pairs[e] & (BNODES - 1)], 1);
    __syncthreads();
    // exclusive scan of 128 degrees
    int v = (t < BNODES) ? deg[t] : 0;
    if (t < BNODES) s[t] = v;
    __syncthreads();
    for (int off = 1; off < BNODES; off <<= 1) {
        int x = (t >= off && t < BNODES) ? s[t - off] : 0;
        __syncthreads();
        if (t < BNODES) s[t] += x;
        __syncthreads();
    }
    const int n0 = b << BSH;
    if (t < BNODES) {
        int excl = s[t] - v;
        cur[t] = excl;
        if (n0 + t < N) {
            row_start[n0 + t] = rb + excl;
            dinv[n0 + t] = rsqrtf((float)v + 1.0f);   // deg + self-loop
        }
    }
    if (b == gridDim.x - 1 && t == 0) row_start[N] = E;
    __syncthreads();
    // reorder: writes confined to this bucket's contiguous [rb, re) region
    for (int e = rb + t; e < re; e += 256) {
        unsigned p = pairs[e];
        int l = p & (BNODES - 1);
        int slot = atomicAdd(&cur[l], 1);
        csr[rb + slot] = p >> BSH;
    }
}

// ---------------- gather: out[n] = b2 + dinv[n]*(z'[n] + sum_in z'[s]) ----------------
// z' packed bf16x2, row = 64 uints. One wave per node; lane owns channels 2*lane, 2*lane+1.
__global__ __launch_bounds__(256)
void gather_nodes(const unsigned* __restrict__ zq, const unsigned* __restrict__ csr,
                  const int* __restrict__ row_start, const float* __restrict__ dinv,
                  const float* __restrict__ b2, float* __restrict__ out, int N)
{
    const int node = blockIdx.x * 4 + (threadIdx.x >> 6);
    const int lane = threadIdx.x & 63;
    if (node >= N) return;

    float2 zs = bf2f2(zq[(long)node * 64 + lane]);
    float acc0 = zs.x, acc1 = zs.y;

    const int rs = row_start[node];
    const int re = row_start[node + 1];
    int j = rs;
    for (; j + 4 <= re; j += 4) {
        unsigned s0 = csr[j + 0];
        unsigned s1 = csr[j + 1];
        unsigned s2 = csr[j + 2];
        unsigned s3 = csr[j + 3];
        unsigned a = zq[(long)s0 * 64 + lane];
        unsigned b = zq[(long)s1 * 64 + lane];
        unsigned c = zq[(long)s2 * 64 + lane];
        unsigned d = zq[(long)s3 * 64 + lane];
        float2 fa = bf2f2(a), fb = bf2f2(b), fc = bf2f2(c), fd = bf2f2(d);
        acc0 += (fa.x + fb.x) + (fc.x + fd.x);
        acc1 += (fa.y + fb.y) + (fc.y + fd.y);
    }
    for (; j < re; j++) {
        unsigned sN = csr[j];
        float2 f = bf2f2(zq[(long)sN * 64 + lane]);
        acc0 += f.x;
        acc1 += f.y;
    }

    float di = dinv[node];
    float2 o;
    o.x = b2[lane * 2 + 0] + di * acc0;
    o.y = b2[lane * 2 + 1] + di * acc1;
    *(float2*)&out[(long)node * CCH + lane * 2] = o;
}

extern "C" void kernel_launch(void* const* d_in, const int* in_sizes, int n_in,
                              void* d_out, int out_size, void* d_ws, size_t ws_size,
                              hipStream_t stream)
{
    const float* x  = (const float*)d_in[0];
    const int*   ei = (const int*)d_in[1];
    const float* W1 = (const float*)d_in[2];
    const float* b1 = (const float*)d_in[3];
    const float* W2 = (const float*)d_in[4];
    const float* b2 = (const float*)d_in[5];
    float* out = (float*)d_out;

    const int N = in_sizes[0] / F_IN;
    const int E = in_sizes[1] / 2;
    const int* src = ei;
    const int* dst = ei + E;

    char* ws = (char*)d_ws;
    float* h      = (float*)ws;    ws += (size_t)N * CCH * 4;
    unsigned* zq  = (unsigned*)ws; ws += (size_t)N * (CCH / 2) * 4;
    unsigned* prs = (unsigned*)ws; ws += (size_t)E * 4;
    unsigned* csr = (unsigned*)ws; ws += (size_t)E * 4;
    int* rstart   = (int*)ws;      ws += ((size_t)N + 1) * 4;
    float* dinv   = (float*)ws;    ws += (size_t)N * 4;
    int* ghist    = (int*)ws;      ws += NBUCK_PAD * 4;
    int* gbase    = (int*)ws;      ws += (NBUCK_PAD + 1) * 4;
    int* gcursor  = (int*)ws;      ws += NBUCK_PAD * 4;

    const int nchunks = (E + CHUNK - 1) / CHUNK;     // 196
    const int nbuck   = (N + BNODES - 1) / BNODES;   // 782

    // bucket build
    zero1024<<<1, 1024, 0, stream>>>(ghist);
    hist_kernel<<<nchunks, 256, 0, stream>>>(dst, ghist, E);
    scan1024<<<1, 1024, 0, stream>>>(ghist, gbase, gcursor);
    partition_kernel<<<nchunks, 256, 0, stream>>>(src, dst, gcursor, prs, E);
    bucket_csr<<<nbuck, 256, 0, stream>>>(prs, gbase, rstart, dinv, csr, N, E);

    // h = relu(x @ W1^T + b1)  [fp32]
    gemm_tiled<0><<<(N + BM - 1) / BM, 256, 0, stream>>>(x, W1, b1, nullptr, h, nullptr, N, F_IN);
    // z' = (h @ W2^T) * dinv   [packed bf16]
    gemm_tiled<1><<<(N + BM - 1) / BM, 256, 0, stream>>>(h, W2, nullptr, dinv, nullptr, zq, N, CCH);

    // aggregate
    gather_nodes<<<(N + 3) / 4, 256, 0, stream>>>(zq, csr, rstart, dinv, b2, out, N);
}

// Round 5
// 355.712 us; speedup vs baseline: 4.7920x; 1.2515x over previous
//
#include <hip/hip_runtime.h>

typedef unsigned short ushort;
typedef __bf16 bf16x8 __attribute__((ext_vector_type(8)));
typedef float f32x4 __attribute__((ext_vector_type(4)));

#define F_IN 256
#define CCH  128
#define BSH  7
#define BNODES 128
#define NBUCK_PAD 1024
#define CHUNK 8192

#define LDA 40    // ushort stride of staged A/B rows (BK=32 + 8 pad)
#define EPS 152   // ushort stride of epilogue tile rows (304 B, 16B-aligned)

// ---------------- helpers: bf16 pack/unpack ----------------
__device__ __forceinline__ ushort f2bf(float f) {
    union { float f; unsigned i; } u; u.f = f;
    unsigned r = u.i + 0x7fffu + ((u.i >> 16) & 1u);   // RNE
    return (ushort)(r >> 16);
}
__device__ __forceinline__ float2 bf2f2(unsigned u) {
    union { unsigned i; float f; } lo, hi;
    lo.i = u << 16;
    hi.i = u & 0xffff0000u;
    return make_float2(lo.f, hi.f);
}

// ---------------- weight fp32 -> bf16 ----------------
__global__ void cvt_w(const float* __restrict__ w, ushort* __restrict__ wb, int n) {
    int i = blockIdx.x * 256 + threadIdx.x;
    if (i < n) wb[i] = f2bf(w[i]);
}

// ---------------- MFMA GEMM: C[M,128] = epi(A[M,K] @ Wb[128,K]^T), bf16 out ----------------
// MODE 0: A fp32; epi = relu(acc + bias)        -> h (bf16 rows)
// MODE 1: A bf16; epi = acc * dinv[row]         -> z' (bf16 rows == packed uint pairs)
template<int MODE>
__global__ __launch_bounds__(256)
void gemm_mfma(const void* __restrict__ Ain, const ushort* __restrict__ Wb,
               const float* __restrict__ bias, const float* __restrict__ dinv,
               ushort* __restrict__ Cout, int M, int K)
{
    __shared__ ushort smem[128 * EPS];      // 38912 B; K-loop uses first 20480 B as As|Bs
    ushort* As = smem;                      // [128][LDA]
    ushort* Bs = smem + 128 * LDA;          // [128][LDA]
    const int tid = threadIdx.x;
    const int wave = tid >> 6, lane = tid & 63;
    const int wm = (wave & 1) * 64, wn = (wave >> 1) * 64;   // 2x2 wave grid
    const int lr = lane & 15;   // index within 16 (m for A, n for B, col for C)
    const int lq = lane >> 4;   // quad (k-octet for A/B, row-quad for C)
    const int m0 = blockIdx.x * 128;

    f32x4 acc[4][4] = {};

    for (int k0 = 0; k0 < K; k0 += 32) {
        if (MODE == 0) {
            const float* A = (const float*)Ain;
#pragma unroll
            for (int it = 0; it < 2; it++) {
                int flat = tid + it * 256;               // 0..511
                int row = flat >> 2, kq = (flat & 3) * 8;
                float4 a0 = make_float4(0.f, 0.f, 0.f, 0.f);
                float4 a1 = make_float4(0.f, 0.f, 0.f, 0.f);
                if (m0 + row < M) {
                    a0 = *(const float4*)&A[(long)(m0 + row) * K + k0 + kq];
                    a1 = *(const float4*)&A[(long)(m0 + row) * K + k0 + kq + 4];
                }
                ushort u[8] = { f2bf(a0.x), f2bf(a0.y), f2bf(a0.z), f2bf(a0.w),
                                f2bf(a1.x), f2bf(a1.y), f2bf(a1.z), f2bf(a1.w) };
                *(uint4*)&As[row * LDA + kq] = *(uint4*)u;
            }
        } else {
            const ushort* A = (const ushort*)Ain;
#pragma unroll
            for (int it = 0; it < 2; it++) {
                int flat = tid + it * 256;
                int row = flat >> 2, kq = (flat & 3) * 8;
                uint4 a = make_uint4(0u, 0u, 0u, 0u);
                if (m0 + row < M)
                    a = *(const uint4*)&A[(long)(m0 + row) * K + k0 + kq];
                *(uint4*)&As[row * LDA + kq] = a;
            }
        }
#pragma unroll
        for (int it = 0; it < 2; it++) {
            int flat = tid + it * 256;
            int row = flat >> 2, kq = (flat & 3) * 8;
            uint4 b = *(const uint4*)&Wb[(long)row * K + k0 + kq];
            *(uint4*)&Bs[row * LDA + kq] = b;
        }
        __syncthreads();

        bf16x8 af[4], bfr[4];
#pragma unroll
        for (int t4 = 0; t4 < 4; t4++) {
            af[t4]  = *(bf16x8*)&As[(wm + t4 * 16 + lr) * LDA + lq * 8];
            bfr[t4] = *(bf16x8*)&Bs[(wn + t4 * 16 + lr) * LDA + lq * 8];
        }
#pragma unroll
        for (int i = 0; i < 4; i++)
#pragma unroll
            for (int j = 0; j < 4; j++)
                acc[i][j] = __builtin_amdgcn_mfma_f32_16x16x32_bf16(af[i], bfr[j], acc[i][j], 0, 0, 0);
        __syncthreads();
    }

    // epilogue: acc (C-layout) -> bf16 -> smem[128][EPS] -> coalesced store
    if (MODE == 0) {
        float bv[4];
#pragma unroll
        for (int j = 0; j < 4; j++) bv[j] = bias[wn + j * 16 + lr];
#pragma unroll
        for (int i = 0; i < 4; i++)
#pragma unroll
            for (int r = 0; r < 4; r++) {
                int row = wm + i * 16 + lq * 4 + r;
#pragma unroll
                for (int j = 0; j < 4; j++) {
                    float v = fmaxf(acc[i][j][r] + bv[j], 0.f);
                    smem[row * EPS + wn + j * 16 + lr] = f2bf(v);
                }
            }
    } else {
#pragma unroll
        for (int i = 0; i < 4; i++)
#pragma unroll
            for (int r = 0; r < 4; r++) {
                int row = wm + i * 16 + lq * 4 + r;
                float di = (m0 + row < M) ? dinv[m0 + row] : 0.f;
#pragma unroll
                for (int j = 0; j < 4; j++)
                    smem[row * EPS + wn + j * 16 + lr] = f2bf(acc[i][j][r] * di);
            }
    }
    __syncthreads();
    {
        int colq = tid & 15, row0 = tid >> 4;
#pragma unroll
        for (int i = 0; i < 8; i++) {
            int row = row0 + i * 16;
            if (m0 + row < M)
                *(uint4*)&Cout[(long)(m0 + row) * CCH + colq * 8] =
                    *(uint4*)&smem[row * EPS + colq * 8];
        }
    }
}

// ---------------- bucket build ----------------
__global__ void zero1024(int* g) { g[threadIdx.x] = 0; }

__global__ __launch_bounds__(256)
void hist_kernel(const int* __restrict__ dst, int* __restrict__ ghist, int E)
{
    __shared__ int h[NBUCK_PAD];
    int t = threadIdx.x;
    for (int i = t; i < NBUCK_PAD; i += 256) h[i] = 0;
    __syncthreads();
    int cb = blockIdx.x * CHUNK;
    int ce = min(cb + CHUNK, E);
    for (int e = cb + t; e < ce; e += 256)
        atomicAdd(&h[dst[e] >> BSH], 1);
    __syncthreads();
    for (int i = t; i < NBUCK_PAD; i += 256)
        if (h[i]) atomicAdd(&ghist[i], h[i]);
}

__global__ void scan1024(const int* __restrict__ ghist, int* __restrict__ base,
                         int* __restrict__ cursor)
{
    __shared__ int s[NBUCK_PAD];
    int t = threadIdx.x;   // 1024 threads
    int v = ghist[t];
    s[t] = v;
    __syncthreads();
    for (int off = 1; off < 1024; off <<= 1) {
        int x = (t >= off) ? s[t - off] : 0;
        __syncthreads();
        s[t] += x;
        __syncthreads();
    }
    int excl = s[t] - v;
    base[t] = excl;
    cursor[t] = excl;
    if (t == 1023) base[1024] = s[t];
}

__global__ __launch_bounds__(256)
void partition_kernel(const int* __restrict__ src, const int* __restrict__ dst,
                      int* __restrict__ cursor, unsigned* __restrict__ pairs, int E)
{
    __shared__ int lhist[NBUCK_PAD];
    __shared__ int lbase[NBUCK_PAD];
    __shared__ int rbase[NBUCK_PAD];
    __shared__ int ssum[256];
    __shared__ uint2 staged[CHUNK];     // 64 KB
    int t = threadIdx.x;
    for (int i = t; i < NBUCK_PAD; i += 256) lhist[i] = 0;
    __syncthreads();
    int cb = blockIdx.x * CHUNK;
    int ce = min(cb + CHUNK, E);
    for (int e = cb + t; e < ce; e += 256)
        atomicAdd(&lhist[dst[e] >> BSH], 1);
    __syncthreads();
    int a0 = lhist[4 * t], a1 = lhist[4 * t + 1], a2 = lhist[4 * t + 2], a3 = lhist[4 * t + 3];
    int tsum = a0 + a1 + a2 + a3;
    ssum[t] = tsum;
    __syncthreads();
    for (int off = 1; off < 256; off <<= 1) {
        int x = (t >= off) ? ssum[t - off] : 0;
        __syncthreads();
        ssum[t] += x;
        __syncthreads();
    }
    int texcl = ssum[t] - tsum;
    lbase[4 * t]     = texcl;
    lbase[4 * t + 1] = texcl + a0;
    lbase[4 * t + 2] = texcl + a0 + a1;
    lbase[4 * t + 3] = texcl + a0 + a1 + a2;
    for (int i = t; i < NBUCK_PAD; i += 256) {
        int c = lhist[i];
        rbase[i] = c ? atomicAdd(&cursor[i], c) : 0;
        lhist[i] = 0;
    }
    __syncthreads();
    for (int e = cb + t; e < ce; e += 256) {
        int d = dst[e];
        int b = d >> BSH;
        unsigned packed = ((unsigned)src[e] << BSH) | (unsigned)(d & (BNODES - 1));
        int p = lbase[b] + atomicAdd(&lhist[b], 1);
        staged[p] = make_uint2(packed, (unsigned)b);
    }
    __syncthreads();
    int cnt = ce - cb;
    for (int i = t; i < cnt; i += 256) {
        uint2 sp = staged[i];
        int b = (int)sp.y;
        pairs[rbase[b] + (i - lbase[b])] = sp.x;
    }
}

__global__ __launch_bounds__(256)
void bucket_csr(const unsigned* __restrict__ pairs, const int* __restrict__ base,
                int* __restrict__ row_start, float* __restrict__ dinv,
                unsigned* __restrict__ csr, int N, int E)
{
    __shared__ int deg[BNODES];
    __shared__ int s[BNODES];
    __shared__ int cur[BNODES];
    const int b = blockIdx.x, t = threadIdx.x;
    if (t < BNODES) deg[t] = 0;
    __syncthreads();
    const int rb = base[b], re = base[b + 1];
    for (int e = rb + t; e < re; e += 256)
        atomicAdd(&deg[pairs[e] & (BNODES - 1)], 1);
    __syncthreads();
    int v = (t < BNODES) ? deg[t] : 0;
    if (t < BNODES) s[t] = v;
    __syncthreads();
    for (int off = 1; off < BNODES; off <<= 1) {
        int x = (t >= off && t < BNODES) ? s[t - off] : 0;
        __syncthreads();
        if (t < BNODES) s[t] += x;
        __syncthreads();
    }
    const int n0 = b << BSH;
    if (t < BNODES) {
        int excl = s[t] - v;
        cur[t] = excl;
        if (n0 + t < N) {
            row_start[n0 + t] = rb + excl;
            dinv[n0 + t] = rsqrtf((float)v + 1.0f);
        }
    }
    if (b == gridDim.x - 1 && t == 0) row_start[N] = E;
    __syncthreads();
    for (int e = rb + t; e < re; e += 256) {
        unsigned p = pairs[e];
        int l = p & (BNODES - 1);
        int slot = atomicAdd(&cur[l], 1);
        csr[rb + slot] = p >> BSH;
    }
}

// ---------------- gather: out[n] = b2 + dinv[n]*(z'[n] + sum_in z'[s]) ----------------
__global__ __launch_bounds__(256)
void gather_nodes(const unsigned* __restrict__ zq, const unsigned* __restrict__ csr,
                  const int* __restrict__ row_start, const float* __restrict__ dinv,
                  const float* __restrict__ b2, float* __restrict__ out, int N)
{
    const int node = blockIdx.x * 4 + (threadIdx.x >> 6);
    const int lane = threadIdx.x & 63;
    if (node >= N) return;

    float2 zs = bf2f2(zq[(long)node * 64 + lane]);
    float acc0 = zs.x, acc1 = zs.y;

    const int rs = row_start[node];
    const int re = row_start[node + 1];
    int j = rs;
    for (; j + 8 <= re; j += 8) {
        unsigned sI[8], zv[8];
#pragma unroll
        for (int q = 0; q < 8; q++) sI[q] = csr[j + q];
#pragma unroll
        for (int q = 0; q < 8; q++) zv[q] = zq[(long)sI[q] * 64 + lane];
#pragma unroll
        for (int q = 0; q < 8; q++) { float2 f = bf2f2(zv[q]); acc0 += f.x; acc1 += f.y; }
    }
    for (; j < re; j++) {
        float2 f = bf2f2(zq[(long)csr[j] * 64 + lane]);
        acc0 += f.x; acc1 += f.y;
    }

    float di = dinv[node];
    float2 o;
    o.x = b2[lane * 2 + 0] + di * acc0;
    o.y = b2[lane * 2 + 1] + di * acc1;
    *(float2*)&out[(long)node * CCH + lane * 2] = o;
}

extern "C" void kernel_launch(void* const* d_in, const int* in_sizes, int n_in,
                              void* d_out, int out_size, void* d_ws, size_t ws_size,
                              hipStream_t stream)
{
    const float* x  = (const float*)d_in[0];
    const int*   ei = (const int*)d_in[1];
    const float* W1 = (const float*)d_in[2];
    const float* b1 = (const float*)d_in[3];
    const float* W2 = (const float*)d_in[4];
    const float* b2 = (const float*)d_in[5];
    float* out = (float*)d_out;

    const int N = in_sizes[0] / F_IN;
    const int E = in_sizes[1] / 2;
    const int* src = ei;
    const int* dst = ei + E;

    char* ws = (char*)d_ws;
    ushort* h     = (ushort*)ws;   ws += (size_t)N * CCH * 2;
    ushort* zq    = (ushort*)ws;   ws += (size_t)N * CCH * 2;
    ushort* w1b   = (ushort*)ws;   ws += (size_t)CCH * F_IN * 2;
    ushort* w2b   = (ushort*)ws;   ws += (size_t)CCH * CCH * 2;
    unsigned* prs = (unsigned*)ws; ws += (size_t)E * 4;
    unsigned* csr = (unsigned*)ws; ws += (size_t)E * 4;
    int* rstart   = (int*)ws;      ws += ((size_t)N + 1) * 4;
    float* dinv   = (float*)ws;    ws += (size_t)N * 4;
    int* ghist    = (int*)ws;      ws += NBUCK_PAD * 4;
    int* gbase    = (int*)ws;      ws += (NBUCK_PAD + 1) * 4;
    int* gcursor  = (int*)ws;      ws += NBUCK_PAD * 4;

    const int nchunks = (E + CHUNK - 1) / CHUNK;
    const int nbuck   = (N + BNODES - 1) / BNODES;
    const int ngrid   = (N + 127) / 128;

    // bucket build (dinv before gemm<1>)
    zero1024<<<1, 1024, 0, stream>>>(ghist);
    hist_kernel<<<nchunks, 256, 0, stream>>>(dst, ghist, E);
    scan1024<<<1, 1024, 0, stream>>>(ghist, gbase, gcursor);
    partition_kernel<<<nchunks, 256, 0, stream>>>(src, dst, gcursor, prs, E);
    bucket_csr<<<nbuck, 256, 0, stream>>>(prs, gbase, rstart, dinv, csr, N, E);

    // weights -> bf16
    cvt_w<<<(CCH * F_IN + 255) / 256, 256, 0, stream>>>(W1, w1b, CCH * F_IN);
    cvt_w<<<(CCH * CCH + 255) / 256, 256, 0, stream>>>(W2, w2b, CCH * CCH);

    // h = relu(x @ W1^T + b1)  [bf16 out]
    gemm_mfma<0><<<ngrid, 256, 0, stream>>>(x, w1b, b1, nullptr, h, N, F_IN);
    // z' = (h @ W2^T) * dinv   [bf16 out == packed pairs]
    gemm_mfma<1><<<ngrid, 256, 0, stream>>>(h, w2b, nullptr, dinv, zq, N, CCH);

    // aggregate
    gather_nodes<<<(N + 3) / 4, 256, 0, stream>>>((const unsigned*)zq, csr, rstart, dinv, b2, out, N);
}

// Round 6
// 338.312 us; speedup vs baseline: 5.0385x; 1.0514x over previous
//
#include <hip/hip_runtime.h>

typedef unsigned short ushort;
typedef __bf16 bf16x8 __attribute__((ext_vector_type(8)));
typedef float f32x4 __attribute__((ext_vector_type(4)));

#define F_IN 256
#define CCH  128
#define BSH  7
#define BNODES 128
#define NBUCK 1024
#define CHUNK 8192

#define LDA 40    // ushort stride of staged A/B rows (BK=32 + 8 pad)
#define LDH 136   // ushort stride of h-tile / epilogue tile rows (272 B, 16B-aligned)

// ---------------- helpers: bf16 pack/unpack ----------------
__device__ __forceinline__ ushort f2bf(float f) {
    union { float f; unsigned i; } u; u.f = f;
    unsigned r = u.i + 0x7fffu + ((u.i >> 16) & 1u);   // RNE
    return (ushort)(r >> 16);
}
__device__ __forceinline__ float2 bf2f2(unsigned u) {
    union { unsigned i; float f; } lo, hi;
    lo.i = u << 16;
    hi.i = u & 0xffff0000u;
    return make_float2(lo.f, hi.f);
}

// ---------------- K1: per-chunk histogram (no global atomics) + weight cvt ----------------
__global__ __launch_bounds__(256)
void hist_cvt(const int* __restrict__ dst, int* __restrict__ hist2D, int E, int nchunks,
              const float* __restrict__ W1, const float* __restrict__ W2,
              ushort* __restrict__ w1b, ushort* __restrict__ w2b)
{
    const int blk = blockIdx.x, t = threadIdx.x;
    if (blk >= nchunks) {
        int i = (blk - nchunks) * 256 + t;
        if (i < CCH * F_IN) w1b[i] = f2bf(W1[i]);
        else {
            int j = i - CCH * F_IN;
            if (j < CCH * CCH) w2b[j] = f2bf(W2[j]);
        }
        return;
    }
    __shared__ int h[NBUCK];
    for (int i = t; i < NBUCK; i += 256) h[i] = 0;
    __syncthreads();
    int cb = blk * CHUNK, ce = min(cb + CHUNK, E);
    for (int e = cb + t; e < ce; e += 256)
        atomicAdd(&h[dst[e] >> BSH], 1);
    __syncthreads();
    for (int i = t; i < NBUCK; i += 256)
        hist2D[blk * NBUCK + i] = h[i];
}

// ---------------- K2: cross-chunk per-bucket prefix + bucket base scan ----------------
__global__ __launch_bounds__(1024)
void scan2d(const int* __restrict__ hist2D, int* __restrict__ pref2D,
            int* __restrict__ base, int nchunks)
{
    __shared__ int s[NBUCK];
    const int t = threadIdx.x;
    int run = 0;
#pragma unroll 4
    for (int c = 0; c < nchunks; c++) {
        int v = hist2D[c * NBUCK + t];
        pref2D[c * NBUCK + t] = run;
        run += v;
    }
    s[t] = run;
    __syncthreads();
    for (int off = 1; off < NBUCK; off <<= 1) {
        int x = (t >= off) ? s[t - off] : 0;
        __syncthreads();
        s[t] += x;
        __syncthreads();
    }
    base[t] = s[t] - run;   // exclusive
    if (t == NBUCK - 1) base[NBUCK] = s[t];
}

// ---------------- K3: partition (deterministic slots, no global atomics) ----------------
__global__ __launch_bounds__(256)
void partition_kernel(const int* __restrict__ src, const int* __restrict__ dst,
                      const int* __restrict__ hist2D, const int* __restrict__ pref2D,
                      const int* __restrict__ base, unsigned* __restrict__ pairs, int E)
{
    __shared__ int lbase[NBUCK];
    __shared__ int lcur[NBUCK];
    __shared__ int rb2[NBUCK];
    __shared__ int ssum[256];
    __shared__ unsigned sp[CHUNK];   // 32 KB
    __shared__ ushort  sb[CHUNK];    // 16 KB
    const int t = threadIdx.x, blk = blockIdx.x;

    int4 cv = *(const int4*)&hist2D[blk * NBUCK + 4 * t];
    int tsum = cv.x + cv.y + cv.z + cv.w;
    ssum[t] = tsum;
    __syncthreads();
    for (int off = 1; off < 256; off <<= 1) {
        int x = (t >= off) ? ssum[t - off] : 0;
        __syncthreads();
        ssum[t] += x;
        __syncthreads();
    }
    int texcl = ssum[t] - tsum;
    lbase[4 * t]     = texcl;
    lbase[4 * t + 1] = texcl + cv.x;
    lbase[4 * t + 2] = texcl + cv.x + cv.y;
    lbase[4 * t + 3] = texcl + cv.x + cv.y + cv.z;
    lcur[4 * t]     = lbase[4 * t];
    lcur[4 * t + 1] = lbase[4 * t + 1];
    lcur[4 * t + 2] = lbase[4 * t + 2];
    lcur[4 * t + 3] = lbase[4 * t + 3];
    for (int i = t; i < NBUCK; i += 256)
        rb2[i] = base[i] + pref2D[blk * NBUCK + i];
    __syncthreads();

    const int cb = blk * CHUNK, ce = min(cb + CHUNK, E);
    for (int e = cb + t; e < ce; e += 256) {
        int d = dst[e];
        int b = d >> BSH;
        unsigned packed = ((unsigned)src[e] << BSH) | (unsigned)(d & (BNODES - 1));
        int p = atomicAdd(&lcur[b], 1);
        sp[p] = packed;
        sb[p] = (ushort)b;
    }
    __syncthreads();
    const int cnt = ce - cb;
    for (int i = t; i < cnt; i += 256) {
        int b = sb[i];
        pairs[rb2[b] + (i - lbase[b])] = sp[i];
    }
}

// ---------------- K4: per-bucket CSR finalize ----------------
__global__ __launch_bounds__(256)
void bucket_csr(const unsigned* __restrict__ pairs, const int* __restrict__ base,
                int* __restrict__ row_start, float* __restrict__ dinv,
                unsigned* __restrict__ csr, int N, int E)
{
    __shared__ int deg[BNODES];
    __shared__ int s[BNODES];
    __shared__ int cur[BNODES];
    const int b = blockIdx.x, t = threadIdx.x;
    if (t < BNODES) deg[t] = 0;
    __syncthreads();
    const int rb = base[b], re = base[b + 1];
    for (int e = rb + t; e < re; e += 256)
        atomicAdd(&deg[pairs[e] & (BNODES - 1)], 1);
    __syncthreads();
    int v = (t < BNODES) ? deg[t] : 0;
    if (t < BNODES) s[t] = v;
    __syncthreads();
    for (int off = 1; off < BNODES; off <<= 1) {
        int x = (t >= off && t < BNODES) ? s[t - off] : 0;
        __syncthreads();
        if (t < BNODES) s[t] += x;
        __syncthreads();
    }
    const int n0 = b << BSH;
    if (t < BNODES) {
        int excl = s[t] - v;
        cur[t] = excl;
        if (n0 + t < N) {
            row_start[n0 + t] = rb + excl;
            dinv[n0 + t] = rsqrtf((float)v + 1.0f);
        }
    }
    if (b == gridDim.x - 1 && t == 0) row_start[N] = E;
    __syncthreads();
    for (int e = rb + t; e < re; e += 256) {
        unsigned p = pairs[e];
        int l = p & (BNODES - 1);
        int slot = atomicAdd(&cur[l], 1);
        csr[rb + slot] = p >> BSH;
    }
}

// ---------------- K5: fused GEMM: z' = (relu(x@W1^T+b1) @ W2^T) * dinv, bf16 out ----------------
__global__ __launch_bounds__(256)
void gemm_fused(const float* __restrict__ X, const ushort* __restrict__ W1b,
                const ushort* __restrict__ W2b, const float* __restrict__ b1,
                const float* __restrict__ dinv, ushort* __restrict__ Zq, int M)
{
    __shared__ ushort As[128 * LDA];   // 10.0 KB
    __shared__ ushort Bs[128 * LDA];   // 10.0 KB
    __shared__ ushort Ht[128 * LDH];   // 34.0 KB  (h-tile, then epilogue staging)
    const int tid = threadIdx.x;
    const int wave = tid >> 6, lane = tid & 63;
    const int wm = (wave & 1) * 64, wn = (wave >> 1) * 64;
    const int lr = lane & 15, lq = lane >> 4;
    const int m0 = blockIdx.x * 128;

    // ---- phase A: acc = x @ W1^T  (K = 256, fp32 A converted on the fly) ----
    f32x4 acc[4][4] = {};
    for (int k0 = 0; k0 < F_IN; k0 += 32) {
#pragma unroll
        for (int it = 0; it < 2; it++) {
            int flat = tid + it * 256;
            int row = flat >> 2, kq = (flat & 3) * 8;
            float4 a0 = make_float4(0.f, 0.f, 0.f, 0.f);
            float4 a1 = make_float4(0.f, 0.f, 0.f, 0.f);
            if (m0 + row < M) {
                a0 = *(const float4*)&X[(long)(m0 + row) * F_IN + k0 + kq];
                a1 = *(const float4*)&X[(long)(m0 + row) * F_IN + k0 + kq + 4];
            }
            ushort u[8] = { f2bf(a0.x), f2bf(a0.y), f2bf(a0.z), f2bf(a0.w),
                            f2bf(a1.x), f2bf(a1.y), f2bf(a1.z), f2bf(a1.w) };
            *(uint4*)&As[row * LDA + kq] = *(uint4*)u;
        }
#pragma unroll
        for (int it = 0; it < 2; it++) {
            int flat = tid + it * 256;
            int row = flat >> 2, kq = (flat & 3) * 8;
            *(uint4*)&Bs[row * LDA + kq] = *(const uint4*)&W1b[(long)row * F_IN + k0 + kq];
        }
        __syncthreads();
        bf16x8 af[4], bfr[4];
#pragma unroll
        for (int t4 = 0; t4 < 4; t4++) {
            af[t4]  = *(bf16x8*)&As[(wm + t4 * 16 + lr) * LDA + lq * 8];
            bfr[t4] = *(bf16x8*)&Bs[(wn + t4 * 16 + lr) * LDA + lq * 8];
        }
#pragma unroll
        for (int i = 0; i < 4; i++)
#pragma unroll
            for (int j = 0; j < 4; j++)
                acc[i][j] = __builtin_amdgcn_mfma_f32_16x16x32_bf16(af[i], bfr[j], acc[i][j], 0, 0, 0);
        __syncthreads();
    }
    // ---- epilogue A: h = relu(acc + b1) -> Ht (bf16, A-fragment-friendly row-major) ----
    {
        float bv[4];
#pragma unroll
        for (int j = 0; j < 4; j++) bv[j] = b1[wn + j * 16 + lr];
#pragma unroll
        for (int i = 0; i < 4; i++)
#pragma unroll
            for (int r = 0; r < 4; r++) {
                int row = wm + i * 16 + lq * 4 + r;
#pragma unroll
                for (int j = 0; j < 4; j++)
                    Ht[row * LDH + wn + j * 16 + lr] = f2bf(fmaxf(acc[i][j][r] + bv[j], 0.f));
            }
    }
    __syncthreads();

    // ---- phase B: acc2 = h @ W2^T  (K = 128, A from LDS Ht) ----
    f32x4 acc2[4][4] = {};
    for (int k0 = 0; k0 < CCH; k0 += 32) {
#pragma unroll
        for (int it = 0; it < 2; it++) {
            int flat = tid + it * 256;
            int row = flat >> 2, kq = (flat & 3) * 8;
            *(uint4*)&Bs[row * LDA + kq] = *(const uint4*)&W2b[(long)row * CCH + k0 + kq];
        }
        __syncthreads();
        bf16x8 af[4], bfr[4];
#pragma unroll
        for (int t4 = 0; t4 < 4; t4++) {
            af[t4]  = *(bf16x8*)&Ht[(wm + t4 * 16 + lr) * LDH + k0 + lq * 8];
            bfr[t4] = *(bf16x8*)&Bs[(wn + t4 * 16 + lr) * LDA + lq * 8];
        }
#pragma unroll
        for (int i = 0; i < 4; i++)
#pragma unroll
            for (int j = 0; j < 4; j++)
                acc2[i][j] = __builtin_amdgcn_mfma_f32_16x16x32_bf16(af[i], bfr[j], acc2[i][j], 0, 0, 0);
        __syncthreads();
    }
    // ---- epilogue B: z' = acc2 * dinv -> Ht (reuse) -> coalesced store ----
#pragma unroll
    for (int i = 0; i < 4; i++)
#pragma unroll
        for (int r = 0; r < 4; r++) {
            int row = wm + i * 16 + lq * 4 + r;
            float di = (m0 + row < M) ? dinv[m0 + row] : 0.f;
#pragma unroll
            for (int j = 0; j < 4; j++)
                Ht[row * LDH + wn + j * 16 + lr] = f2bf(acc2[i][j][r] * di);
        }
    __syncthreads();
    {
        int colq = tid & 15, row0 = tid >> 4;
#pragma unroll
        for (int i = 0; i < 8; i++) {
            int row = row0 + i * 16;
            if (m0 + row < M)
                *(uint4*)&Zq[(long)(m0 + row) * CCH + colq * 8] =
                    *(uint4*)&Ht[row * LDH + colq * 8];
        }
    }
}

// ---------------- K6: gather: out[n] = b2 + dinv[n]*(z'[n] + sum_in z'[s]) ----------------
__global__ __launch_bounds__(256)
void gather_nodes(const unsigned* __restrict__ zq, const unsigned* __restrict__ csr,
                  const int* __restrict__ row_start, const float* __restrict__ dinv,
                  const float* __restrict__ b2, float* __restrict__ out, int N)
{
    const int node = blockIdx.x * 4 + (threadIdx.x >> 6);
    const int lane = threadIdx.x & 63;
    if (node >= N) return;

    float2 zs = bf2f2(zq[(long)node * 64 + lane]);
    float acc0 = zs.x, acc1 = zs.y;

    const int rs = row_start[node];
    const int re = row_start[node + 1];
    int j = rs;
    for (; j + 8 <= re; j += 8) {
        unsigned sI[8], zv[8];
#pragma unroll
        for (int q = 0; q < 8; q++) sI[q] = csr[j + q];
#pragma unroll
        for (int q = 0; q < 8; q++) zv[q] = zq[(long)sI[q] * 64 + lane];
#pragma unroll
        for (int q = 0; q < 8; q++) { float2 f = bf2f2(zv[q]); acc0 += f.x; acc1 += f.y; }
    }
    for (; j < re; j++) {
        float2 f = bf2f2(zq[(long)csr[j] * 64 + lane]);
        acc0 += f.x; acc1 += f.y;
    }

    float di = dinv[node];
    float2 o;
    o.x = b2[lane * 2 + 0] + di * acc0;
    o.y = b2[lane * 2 + 1] + di * acc1;
    *(float2*)&out[(long)node * CCH + lane * 2] = o;
}

extern "C" void kernel_launch(void* const* d_in, const int* in_sizes, int n_in,
                              void* d_out, int out_size, void* d_ws, size_t ws_size,
                              hipStream_t stream)
{
    const float* x  = (const float*)d_in[0];
    const int*   ei = (const int*)d_in[1];
    const float* W1 = (const float*)d_in[2];
    const float* b1 = (const float*)d_in[3];
    const float* W2 = (const float*)d_in[4];
    const float* b2 = (const float*)d_in[5];
    float* out = (float*)d_out;

    const int N = in_sizes[0] / F_IN;
    const int E = in_sizes[1] / 2;
    const int* src = ei;
    const int* dst = ei + E;

    const int nchunks = (E + CHUNK - 1) / CHUNK;     // 196
    const int nbuck   = (N + BNODES - 1) / BNODES;   // 782
    const int ngrid   = (N + 127) / 128;
    const int ncvt    = (CCH * F_IN + CCH * CCH + 255) / 256;   // 192

    char* ws = (char*)d_ws;
    ushort* zq    = (ushort*)ws;   ws += (size_t)N * CCH * 2;
    ushort* w1b   = (ushort*)ws;   ws += (size_t)CCH * F_IN * 2;
    ushort* w2b   = (ushort*)ws;   ws += (size_t)CCH * CCH * 2;
    unsigned* prs = (unsigned*)ws; ws += (size_t)E * 4;
    unsigned* csr = (unsigned*)ws; ws += (size_t)E * 4;
    int* rstart   = (int*)ws;      ws += ((size_t)N + 1) * 4;
    float* dinv   = (float*)ws;    ws += (size_t)N * 4;
    int* hist2D   = (int*)ws;      ws += (size_t)nchunks * NBUCK * 4;
    int* pref2D   = (int*)ws;      ws += (size_t)nchunks * NBUCK * 4;
    int* gbase    = (int*)ws;      ws += (NBUCK + 1) * 4;

    // build
    hist_cvt<<<nchunks + ncvt, 256, 0, stream>>>(dst, hist2D, E, nchunks, W1, W2, w1b, w2b);
    scan2d<<<1, 1024, 0, stream>>>(hist2D, pref2D, gbase, nchunks);
    partition_kernel<<<nchunks, 256, 0, stream>>>(src, dst, hist2D, pref2D, gbase, prs, E);
    bucket_csr<<<nbuck, 256, 0, stream>>>(prs, gbase, rstart, dinv, csr, N, E);

    // fused GEMMs: z' = (relu(x@W1^T + b1) @ W2^T) * dinv   [bf16]
    gemm_fused<<<ngrid, 256, 0, stream>>>(x, w1b, w2b, b1, dinv, zq, N);

    // aggregate
    gather_nodes<<<(N + 3) / 4, 256, 0, stream>>>((const unsigned*)zq, csr, rstart, dinv, b2, out, N);
}